// Round 13
// baseline (694.863 us; speedup 1.0000x reference)
//
#include <hip/hip_runtime.h>
#include <hip/hip_bf16.h>

typedef unsigned short u16;
typedef __attribute__((ext_vector_type(8))) short short8;
typedef __attribute__((ext_vector_type(4))) short short4v;
typedef __attribute__((ext_vector_type(4))) float f32x4;

#define HEADS 20
#define HD 64
#define BB 8
#define SQ 4096
#define HDIM 1280
#define SKV 109
#define CDIM 768
#define SKV_PAD 128
#define SKV_T 112

#define SBAR() asm volatile("s_barrier" ::: "memory")

static __device__ __forceinline__ u16 f2bf(float x) {
  union { __hip_bfloat16 h; u16 u; } cv;
  cv.h = __float2bfloat16(x);
  return cv.u;
}

// async global->LDS, 16B per lane (dest = wave-uniform base + lane*16).
static __device__ __forceinline__ void gll16(const void* g, void* l) {
  __builtin_amdgcn_global_load_lds(
      (const __attribute__((address_space(1))) unsigned int*)g,
      (__attribute__((address_space(3))) unsigned int*)l, 16, 0, 0);
}

// ---- prep: out[n][k] = bf16(W[k][n] * scale)  (W is K x N row-major)
__global__ __launch_bounds__(256) void tcvt(const float* __restrict__ W,
                                            u16* __restrict__ out, int K, int N,
                                            float scale) {
  __shared__ float t[32][33];
  int tx = threadIdx.x & 31, ty = threadIdx.x >> 5;
  int n0 = blockIdx.x * 32, k0 = blockIdx.y * 32;
#pragma unroll
  for (int i = 0; i < 32; i += 8)
    t[ty + i][tx] = W[(size_t)(k0 + ty + i) * N + n0 + tx];
  __syncthreads();
#pragma unroll
  for (int i = 0; i < 32; i += 8)
    out[(size_t)(n0 + ty + i) * K + k0 + tx] = f2bf(t[tx][ty + i] * scale);
}

// ---- prep: encoder states f32 (8,109,768) -> bf16 (8,128,768), zero pad rows
__global__ __launch_bounds__(256) void ehs_prep(const float* __restrict__ e,
                                                u16* __restrict__ out) {
  int idx = blockIdx.x * 256 + threadIdx.x;
  if (idx >= BB * SKV_PAD * CDIM / 4) return;
  int c4 = idx * 4;
  int b = c4 / (SKV_PAD * CDIM);
  int rem = c4 - b * (SKV_PAD * CDIM);
  int s = rem / CDIM;
  int c = rem - s * CDIM;
  short4v o = {0, 0, 0, 0};
  if (s < SKV) {
    f32x4 v = *(const f32x4*)(e + ((size_t)b * SKV + s) * CDIM + c);
#pragma unroll
    for (int j = 0; j < 4; j++) o[j] = (short)f2bf(v[j]);
  }
  *(short4v*)&out[c4] = o;
}

// ======= Q-projection: f32 A direct from global (hscvt fused away) ==========
// BM=128, BN=256, BK=32; 8 waves (2Mx4N), 64x64/wave. B: 3-buf LDS DMA
// (r8-proven counted-vmcnt). A: per-lane f32x4 loads -> regs -> f2bf -> MFMA.
// A tile (16KB f32) is L1-resident; wn-duplicate reads hit L1. Per-frag access
// = 16 rows x 128B contiguous segments (coalesced).
// Ledger: per iter issue {A(t):8 ld, B(t+2):2 DMA}; vmcnt(2) after B ds_reads
// retires A(t) + B(t+1) (early-retire of B(t+1) harmless: ~1 tile of flight).
// bf16 row-major out.
__global__ __launch_bounds__(512, 4)
void gemm_qp(const float* __restrict__ A, const u16* __restrict__ Bt,
             u16* __restrict__ O, int K, int ntn) {
  __shared__ u16 lds[3][8192];  // B only: 256 x 32 bf16 per buf
  const int tid = threadIdx.x;
  const int wid = tid >> 6, lane = tid & 63;
  const int wm = wid >> 2, wn = wid & 3;
  const int g = lane >> 4, r = lane & 15;

  const int nwg = gridDim.x;
  const int orig = blockIdx.x;
  const int wg = (orig & 7) * (nwg >> 3) + (orig >> 3);  // XCD swizzle
  const int mt = wg / ntn, nt = wg - mt * ntn;
  const int row0 = mt * 128, col0 = nt * 256;

  const float* Ag = A + (size_t)(row0 + wm * 64 + r) * K + g * 8;
  const u16* Bg = Bt + (size_t)col0 * K;
  const int NT = K >> 5;

  const int cx = (g * 8) ^ (((r >> 1) & 3) << 3);

  const int sb_row = tid >> 2;
  const int sb_sc = (tid & 3) ^ ((tid >> 3) & 3);
  const int sb_row1 = (tid + 512) >> 2;
  const int sb_sc1 = ((tid + 512) & 3) ^ (((tid + 512) >> 3) & 3);

  f32x4 acc[4][4] = {};

  auto stageB = [&](int buf, int kt) {
    gll16(Bg + (size_t)sb_row * K + kt + sb_sc * 8, &lds[buf][tid * 8]);
    gll16(Bg + (size_t)sb_row1 * K + kt + sb_sc1 * 8,
          &lds[buf][(tid + 512) * 8]);
  };

  // prologue: B tiles 0,1 in flight; land tile 0 (leave tile 1's 2 ops)
  stageB(0, 0);
  stageB(1, 32);
  asm volatile("s_waitcnt vmcnt(2)" ::: "memory");
  SBAR();

  int buf = 0;
  for (int t = 0; t < NT; ++t) {
    const int kt = t * 32;
    // A(t): 8 f32x4 per lane (2 per frag)
    f32x4 va[4][2];
#pragma unroll
    for (int mi = 0; mi < 4; ++mi) {
      const float* p = Ag + (size_t)(mi * 16) * K + kt;
      va[mi][0] = *(const f32x4*)p;
      va[mi][1] = *(const f32x4*)(p + 4);
    }
    int nb = buf + 2;
    if (nb >= 3) nb -= 3;
    if (t + 2 < NT) stageB(nb, (t + 2) * 32);

    short8 b[4];
#pragma unroll
    for (int nf = 0; nf < 4; ++nf)
      b[nf] = *(short8*)&lds[buf][(wn * 64 + nf * 16 + r) * 32 + cx];

    if (t + 2 < NT)
      asm volatile("s_waitcnt vmcnt(2)" ::: "memory");
    else
      asm volatile("s_waitcnt vmcnt(0)" ::: "memory");

    short8 a[4];
#pragma unroll
    for (int mi = 0; mi < 4; ++mi)
#pragma unroll
      for (int j = 0; j < 4; ++j) {
        a[mi][j] = (short)f2bf(va[mi][0][j]);
        a[mi][j + 4] = (short)f2bf(va[mi][1][j]);
      }

    __builtin_amdgcn_s_setprio(1);
#pragma unroll
    for (int mi = 0; mi < 4; ++mi)
#pragma unroll
      for (int nf = 0; nf < 4; ++nf)
        acc[mi][nf] = __builtin_amdgcn_mfma_f32_16x16x32_bf16(a[mi], b[nf],
                                                              acc[mi][nf], 0, 0, 0);
    __builtin_amdgcn_s_setprio(0);
    SBAR();
    buf = (buf + 1 == 3) ? 0 : buf + 1;
  }

  // epilogue: row = row0 + wm*64 + mi*16 + g*4 + i, col = col0 + wn*64 + nf*16 + r
#pragma unroll
  for (int mi = 0; mi < 4; ++mi)
#pragma unroll
    for (int i = 0; i < 4; ++i) {
      size_t m = row0 + wm * 64 + mi * 16 + g * 4 + i;
      size_t base = m * HDIM + col0 + wn * 64 + r;
#pragma unroll
      for (int nf = 0; nf < 4; ++nf)
        O[base + nf * 16] = f2bf(acc[mi][nf][i]);
    }
}

// ============ 128x256 tile, BK=32, 3-buffer counted-vmcnt GEMM ===============
// r8 skeleton. MODE 3: f32 out + bias + residual (O-projection).
template <int MODE>
__global__ __launch_bounds__(512, 4)
void gemm_v2(const u16* __restrict__ A, const u16* __restrict__ Bt,
             void* __restrict__ outp, int K, int ntn,
             const float* __restrict__ bias, const float* __restrict__ resid) {
  // per buf: A elems [0,4096) = 128x32, B elems [4096,12288) = 256x32
  __shared__ u16 lds[3][12288];
  const int tid = threadIdx.x;
  const int wid = tid >> 6, lane = tid & 63;
  const int wm = wid >> 2, wn = wid & 3;
  const int g = lane >> 4, r = lane & 15;

  const int nwg = gridDim.x;
  const int orig = blockIdx.x;
  const int wg = (orig & 7) * (nwg >> 3) + (orig >> 3);  // XCD swizzle
  const int mt = wg / ntn, nt = wg - mt * ntn;
  const int row0 = mt * 128, col0 = nt * 256;

  const u16* Ag = A + (size_t)row0 * K;
  const u16* Bg = Bt + (size_t)col0 * K;
  const int NT = K >> 5;

  const int cx = (g * 8) ^ (((r >> 1) & 3) << 3);

  const int sa_row = tid >> 2;
  const int sa_sc = (tid & 3) ^ ((tid >> 3) & 3);
  const int sb_row1 = (tid + 512) >> 2;
  const int sb_sc1 = ((tid + 512) & 3) ^ (((tid + 512) >> 3) & 3);

  f32x4 acc[4][4] = {};

  auto stage = [&](int buf, int kt) {
    gll16(Ag + (size_t)sa_row * K + kt + sa_sc * 8, &lds[buf][tid * 8]);
    gll16(Bg + (size_t)sa_row * K + kt + sa_sc * 8, &lds[buf][4096 + tid * 8]);
    gll16(Bg + (size_t)sb_row1 * K + kt + sb_sc1 * 8,
          &lds[buf][4096 + (tid + 512) * 8]);
  };

  stage(0, 0);
  stage(1, 32);
  asm volatile("s_waitcnt vmcnt(3)" ::: "memory");
  SBAR();

  int buf = 0;
  for (int t = 0; t < NT; ++t) {
    int nb = buf + 2;
    if (nb >= 3) nb -= 3;
    if (t + 2 < NT) stage(nb, (t + 2) * 32);

    short8 a[4], b[4];
#pragma unroll
    for (int mi = 0; mi < 4; ++mi)
      a[mi] = *(short8*)&lds[buf][(wm * 64 + mi * 16 + r) * 32 + cx];
#pragma unroll
    for (int nf = 0; nf < 4; ++nf)
      b[nf] = *(short8*)&lds[buf][4096 + (wn * 64 + nf * 16 + r) * 32 + cx];

    __builtin_amdgcn_s_setprio(1);
#pragma unroll
    for (int mi = 0; mi < 4; ++mi)
#pragma unroll
      for (int nf = 0; nf < 4; ++nf)
        acc[mi][nf] = __builtin_amdgcn_mfma_f32_16x16x32_bf16(a[mi], b[nf],
                                                              acc[mi][nf], 0, 0, 0);
    __builtin_amdgcn_s_setprio(0);

    if (t < NT - 2)
      asm volatile("s_waitcnt vmcnt(3)" ::: "memory");
    else
      asm volatile("s_waitcnt vmcnt(0)" ::: "memory");
    SBAR();
    buf = (buf + 1 == 3) ? 0 : buf + 1;
  }

  if constexpr (MODE == 0) {
    u16* O = (u16*)outp;
#pragma unroll
    for (int mi = 0; mi < 4; ++mi)
#pragma unroll
      for (int i = 0; i < 4; ++i) {
        size_t m = row0 + wm * 64 + mi * 16 + g * 4 + i;
        size_t base = m * HDIM + col0 + wn * 64 + r;
#pragma unroll
        for (int nf = 0; nf < 4; ++nf)
          O[base + nf * 16] = f2bf(acc[mi][nf][i]);
      }
  } else {
    float* O = (float*)outp;
#pragma unroll
    for (int mi = 0; mi < 4; ++mi)
#pragma unroll
      for (int i = 0; i < 4; ++i) {
        size_t m = row0 + wm * 64 + mi * 16 + g * 4 + i;
        size_t base = m * HDIM + col0 + wn * 64 + r;
#pragma unroll
        for (int nf = 0; nf < 4; ++nf) {
          int col = col0 + wn * 64 + nf * 16 + r;
          O[base + nf * 16] = acc[mi][nf][i] + bias[col] + resid[base + nf * 16];
        }
      }
  }
}

// ---- merged K+V projection (m97 structure). Grid 160: first 80 blocks = K
// (heads layout), last 80 = V^T layout. Same A; uniform runtime branch.
__global__ __launch_bounds__(256, 4)
void gemm_kv(const u16* __restrict__ A, const u16* __restrict__ Kt,
             const u16* __restrict__ Vt, u16* __restrict__ khb,
             u16* __restrict__ vtb) {
  __shared__ u16 Alds[128 * 32];
  __shared__ u16 Blds[128 * 32];
  const int tid = threadIdx.x;
  const int wid = tid >> 6, lane = tid & 63;
  const int wm = wid >> 1, wn = wid & 1;
  const int g = lane >> 4, r = lane & 15;

  const int half = blockIdx.x >= 80 ? 1 : 0;
  const u16* Bt = half ? Vt : Kt;
  const int orig = blockIdx.x - half * 80;
  const int wg = (orig & 7) * 10 + (orig >> 3);  // XCD swizzle within 80
  const int mt = wg / 10, nt = wg - mt * 10;
  const int row0 = mt * 128, col0 = nt * 128;
  const int erow = tid >> 2, ecol = (tid & 3) * 8;
  const int K = CDIM;

  f32x4 acc[4][4] = {};

  for (int kt = 0; kt < K; kt += 32) {
    const u16* ag = A + (size_t)(row0 + erow) * K + kt + ecol;
    const u16* bg = Bt + (size_t)(col0 + erow) * K + kt + ecol;
    gll16(ag, &Alds[erow * 32 + ecol]);
    gll16(ag + (size_t)64 * K, &Alds[(erow + 64) * 32 + ecol]);
    gll16(bg, &Blds[erow * 32 + ecol]);
    gll16(bg + (size_t)64 * K, &Blds[(erow + 64) * 32 + ecol]);
    __syncthreads();

    short8 afr[4], bfr[4];
#pragma unroll
    for (int mi = 0; mi < 4; mi++)
      afr[mi] = *(short8*)&Alds[(wm * 64 + mi * 16 + r) * 32 + g * 8];
#pragma unroll
    for (int ni = 0; ni < 4; ni++)
      bfr[ni] = *(short8*)&Blds[(wn * 64 + ni * 16 + r) * 32 + g * 8];
#pragma unroll
    for (int mi = 0; mi < 4; mi++)
#pragma unroll
      for (int ni = 0; ni < 4; ni++)
        acc[mi][ni] = __builtin_amdgcn_mfma_f32_16x16x32_bf16(afr[mi], bfr[ni],
                                                              acc[mi][ni], 0, 0, 0);
    __syncthreads();
  }

  u16* O = half ? vtb : khb;
#pragma unroll
  for (int mi = 0; mi < 4; mi++)
#pragma unroll
    for (int i = 0; i < 4; i++) {
      int m = row0 + wm * 64 + mi * 16 + g * 4 + i;
      int b = m >> 7, skv = m & 127;
#pragma unroll
      for (int ni = 0; ni < 4; ni++) {
        int col = col0 + wn * 64 + ni * 16 + r;
        int hh = col >> 6, d = col & 63;
        size_t addr;
        if (half)
          addr = (((size_t)b * HEADS + hh) * HD + d) * SKV_PAD + skv;
        else
          addr = (((size_t)b * HEADS + hh) * SKV_PAD + skv) * HD + d;
        O[addr] = f2bf(acc[mi][ni][i]);
      }
    }
}

// ---- fused attention v2: 8 Q-tiles/block; K/V staged once; per-wave P/Out
// regions -> no barriers in the Q-loop. Q prefetched one iteration ahead.
__global__ __launch_bounds__(256, 2)
void attn_kernel(const u16* __restrict__ q, const u16* __restrict__ kh,
                 const u16* __restrict__ vt, u16* __restrict__ o) {
  __shared__ u16 Klds[SKV_T * 72];     // [skv 112][64+8]
  __shared__ u16 Vlds[HD * 136];       // [64][128+8]
  __shared__ u16 Plds[4 * 16 * 136];   // per-wave P [16][136]
  __shared__ u16 Olds[4 * 16 * 72];    // per-wave out [16][72]
  const int tid = threadIdx.x;
  const int wid = tid >> 6, lane = tid & 63;
  const int g = lane >> 4, r = lane & 15;
  const int bh = blockIdx.y;
  const int b = bh / HEADS, h = bh - b * HEADS;
  const int qt0 = blockIdx.x * 8;

  const u16* kg = kh + (size_t)bh * SKV_PAD * HD;
  for (int i = tid; i < SKV_T * 8; i += 256) {
    int row = i >> 3, c = (i & 7) * 8;
    *(short8*)&Klds[row * 72 + c] = *(const short8*)(kg + row * HD + c);
  }
  const u16* vg = vt + (size_t)bh * HD * SKV_PAD;
  for (int i = tid; i < HD * 16; i += 256) {
    int row = i >> 4, c = (i & 15) * 8;
    *(short8*)&Vlds[row * 136 + c] = *(const short8*)(vg + row * SKV_PAD + c);
  }
  {
    short4v z = {0, 0, 0, 0};
    *(short4v*)&Plds[(wid * 16 + r) * 136 + 112 + g * 4] = z;
  }
  __syncthreads();

  const u16* qbase = q + ((size_t)b * SQ + wid * 16 + r) * HDIM + h * HD + g * 8;
  short8 aq0 = *(const short8*)(qbase + (size_t)qt0 * 64 * HDIM);
  short8 aq1 = *(const short8*)(qbase + (size_t)qt0 * 64 * HDIM + 32);

#pragma unroll 1
  for (int qs = 0; qs < 8; ++qs) {
    const int qt = qt0 + qs;

    f32x4 s[7];
#pragma unroll
    for (int nf = 0; nf < 7; nf++) {
      f32x4 z = {0.f, 0.f, 0.f, 0.f};
      short8 k0 = *(short8*)&Klds[(nf * 16 + r) * 72 + g * 8];
      short8 k1 = *(short8*)&Klds[(nf * 16 + r) * 72 + 32 + g * 8];
      z = __builtin_amdgcn_mfma_f32_16x16x32_bf16(aq0, k0, z, 0, 0, 0);
      z = __builtin_amdgcn_mfma_f32_16x16x32_bf16(aq1, k1, z, 0, 0, 0);
      s[nf] = z;
    }

    if (qs + 1 < 8) {
      aq0 = *(const short8*)(qbase + (size_t)(qt + 1) * 64 * HDIM);
      aq1 = *(const short8*)(qbase + (size_t)(qt + 1) * 64 * HDIM + 32);
    }

#pragma unroll
    for (int i = 0; i < 4; i++) {
      float pv[7];
      float mx = -1e30f;
#pragma unroll
      for (int nf = 0; nf < 7; nf++) {
        float v = s[nf][i];
        if (nf == 6 && r >= 13) v = -1e30f;  // cols >= 109 masked
        pv[nf] = v;
        mx = fmaxf(mx, v);
      }
#pragma unroll
      for (int d = 1; d < 16; d <<= 1) mx = fmaxf(mx, __shfl_xor(mx, d, 64));
      float sum = 0.f;
#pragma unroll
      for (int nf = 0; nf < 7; nf++) {
        float e = (nf == 6 && r >= 13) ? 0.f : __expf(pv[nf] - mx);
        pv[nf] = e;
        sum += e;
      }
#pragma unroll
      for (int d = 1; d < 16; d <<= 1) sum += __shfl_xor(sum, d, 64);
      float is = 1.f / sum;
#pragma unroll
      for (int nf = 0; nf < 7; nf++)
        Plds[(wid * 16 + g * 4 + i) * 136 + nf * 16 + r] = f2bf(pv[nf] * is);
    }

    f32x4 oacc[4] = {};
#pragma unroll
    for (int kk = 0; kk < 4; kk++) {
      short8 ap = *(short8*)&Plds[(wid * 16 + r) * 136 + kk * 32 + g * 8];
#pragma unroll
      for (int nf = 0; nf < 4; nf++) {
        short8 bv = *(short8*)&Vlds[(nf * 16 + r) * 136 + kk * 32 + g * 8];
        oacc[nf] = __builtin_amdgcn_mfma_f32_16x16x32_bf16(ap, bv, oacc[nf], 0, 0, 0);
      }
    }

    u16* st = &Olds[wid * 16 * 72];
#pragma unroll
    for (int nf = 0; nf < 4; nf++)
#pragma unroll
      for (int i = 0; i < 4; i++)
        st[(g * 4 + i) * 72 + nf * 16 + r] = f2bf(oacc[nf][i]);
    u16* og = o + ((size_t)b * SQ + qt * 64 + wid * 16) * HDIM + h * HD;
#pragma unroll
    for (int j = 0; j < 2; ++j) {
      int chunk = lane + j * 64;
      int row = chunk >> 3, cc = (chunk & 7) * 8;
      *(short8*)&og[(size_t)row * HDIM + cc] = *(short8*)&st[row * 72 + cc];
    }
  }
}

extern "C" void kernel_launch(void* const* d_in, const int* in_sizes, int n_in,
                              void* d_out, int out_size, void* d_ws, size_t ws_size,
                              hipStream_t stream) {
  const float* hs  = (const float*)d_in[0];
  const float* ehs = (const float*)d_in[1];
  const float* Wq  = (const float*)d_in[2];
  const float* Wk  = (const float*)d_in[3];
  const float* Wv  = (const float*)d_in[4];
  const float* Wo  = (const float*)d_in[5];
  const float* bo  = (const float*)d_in[6];

  char* ws = (char*)d_ws;
  size_t off = 0;
  auto alloc = [&](size_t elems) {
    u16* p = (u16*)(ws + off);
    off += ((elems * 2 + 255) / 256) * 256;
    return p;
  };
  u16* wqt  = alloc((size_t)HDIM * HDIM);
  u16* wot  = alloc((size_t)HDIM * HDIM);
  u16* wkt  = alloc((size_t)HDIM * CDIM);
  u16* wvt  = alloc((size_t)HDIM * CDIM);
  u16* ehsp = alloc((size_t)BB * SKV_PAD * CDIM);
  u16* khb  = alloc((size_t)BB * HEADS * SKV_PAD * HD);
  u16* vtb  = alloc((size_t)BB * HEADS * HD * SKV_PAD);
  u16* qb   = alloc((size_t)BB * SQ * HDIM);
  u16* ao   = alloc((size_t)BB * SQ * HDIM);

  tcvt<<<dim3(HDIM / 32, HDIM / 32), 256, 0, stream>>>(Wq, wqt, HDIM, HDIM, 0.125f);
  tcvt<<<dim3(HDIM / 32, CDIM / 32), 256, 0, stream>>>(Wk, wkt, CDIM, HDIM, 1.0f);
  tcvt<<<dim3(HDIM / 32, CDIM / 32), 256, 0, stream>>>(Wv, wvt, CDIM, HDIM, 1.0f);
  tcvt<<<dim3(HDIM / 32, HDIM / 32), 256, 0, stream>>>(Wo, wot, HDIM, HDIM, 1.0f);
  ehs_prep<<<dim3((BB * SKV_PAD * CDIM / 4 + 255) / 256), 256, 0, stream>>>(ehs, ehsp);

  // merged K,V projections (grid 160; two 80-block halves, each % 8 == 0)
  gemm_kv<<<dim3(160), 256, 0, stream>>>(ehsp, wkt, wvt, khb, vtb);
  // Q projection straight from f32 hidden_states (hscvt eliminated)
  gemm_qp<<<dim3(1280), 512, 0, stream>>>(hs, wqt, qb, HDIM, 5);
  // attention: 8 Q-tiles per block, K/V staged once
  attn_kernel<<<dim3(SQ / 512, BB * HEADS), 256, 0, stream>>>(qb, khb, vtb, ao);
  // output projection + bias + f32 residual
  gemm_v2<3><<<dim3(1280), 512, 0, stream>>>(ao, wot, (void*)d_out, HDIM, 5, bo, hs);
}

// Round 14
// 392.618 us; speedup vs baseline: 1.7698x; 1.7698x over previous
//
#include <hip/hip_runtime.h>
#include <hip/hip_bf16.h>

typedef unsigned short u16;
typedef __attribute__((ext_vector_type(8))) short short8;
typedef __attribute__((ext_vector_type(4))) short short4v;
typedef __attribute__((ext_vector_type(4))) float f32x4;

#define HEADS 20
#define HD 64
#define BB 8
#define SQ 4096
#define HDIM 1280
#define SKV 109
#define CDIM 768
#define SKV_PAD 128
#define SKV_T 112

#define SBAR() asm volatile("s_barrier" ::: "memory")

static __device__ __forceinline__ u16 f2bf(float x) {
  union { __hip_bfloat16 h; u16 u; } cv;
  cv.h = __float2bfloat16(x);
  return cv.u;
}

// async global->LDS, 16B per lane (dest = wave-uniform base + lane*16).
static __device__ __forceinline__ void gll16(const void* g, void* l) {
  __builtin_amdgcn_global_load_lds(
      (const __attribute__((address_space(1))) unsigned int*)g,
      (__attribute__((address_space(3))) unsigned int*)l, 16, 0, 0);
}

// ---- merged prep: 4 weight transposes + encoder pad/convert, one launch.
// blocks [0,1600) Wq | [1600,2560) Wk | [2560,3520) Wv | [3520,5120) Wo |
// [5120,5888) ehs_prep. Branch is blockIdx-uniform -> __syncthreads safe.
__global__ __launch_bounds__(256) void prep_all(
    const float* __restrict__ Wq, const float* __restrict__ Wk,
    const float* __restrict__ Wv, const float* __restrict__ Wo,
    const float* __restrict__ ehs, u16* __restrict__ wqt,
    u16* __restrict__ wkt, u16* __restrict__ wvt, u16* __restrict__ wot,
    u16* __restrict__ ehsp) {
  const int id = blockIdx.x;
  if (id < 5120) {
    const float* W;
    u16* out;
    int K;
    float scale;
    int base;
    if (id < 1600) {
      W = Wq; out = wqt; K = HDIM; scale = 0.125f; base = 0;
    } else if (id < 2560) {
      W = Wk; out = wkt; K = CDIM; scale = 1.0f; base = 1600;
    } else if (id < 3520) {
      W = Wv; out = wvt; K = CDIM; scale = 1.0f; base = 2560;
    } else {
      W = Wo; out = wot; K = HDIM; scale = 1.0f; base = 3520;
    }
    const int lid = id - base;
    const int bx = lid % 40, by = lid / 40;  // N/32 = 40 (N == HDIM always)
    __shared__ float t[32][33];
    int tx = threadIdx.x & 31, ty = threadIdx.x >> 5;
    int n0 = bx * 32, k0 = by * 32;
#pragma unroll
    for (int i = 0; i < 32; i += 8)
      t[ty + i][tx] = W[(size_t)(k0 + ty + i) * HDIM + n0 + tx];
    __syncthreads();
#pragma unroll
    for (int i = 0; i < 32; i += 8)
      out[(size_t)(n0 + ty + i) * K + k0 + tx] = f2bf(t[tx][ty + i] * scale);
  } else {
    int idx = (id - 5120) * 256 + threadIdx.x;
    if (idx >= BB * SKV_PAD * CDIM / 4) return;
    int c4 = idx * 4;
    int b = c4 / (SKV_PAD * CDIM);
    int rem = c4 - b * (SKV_PAD * CDIM);
    int s = rem / CDIM;
    int c = rem - s * CDIM;
    short4v o = {0, 0, 0, 0};
    if (s < SKV) {
      f32x4 v = *(const f32x4*)(ehs + ((size_t)b * SKV + s) * CDIM + c);
#pragma unroll
      for (int j = 0; j < 4; j++) o[j] = (short)f2bf(v[j]);
    }
    *(short4v*)&ehsp[c4] = o;
  }
}

// ============ 128x256 tile, BK=32, 3-buffer counted-vmcnt GEMM ===============
// r8 skeleton (session best). Per tile: stage t+2 (3 gll16) -> 8 ds_read_b128
// -> 16 MFMA 16x16x32 -> vmcnt(3) -> s_barrier. Swizzle chunk ^= (row>>1)&3
// (conflicts=0). 8 waves (2Mx4N), 64x64/wave; __launch_bounds__(512,4) ->
// 2 blocks/CU. MODE 0: bf16 row-major out. MODE 3: f32 + bias + residual.
template <int MODE>
__global__ __launch_bounds__(512, 4)
void gemm_v2(const u16* __restrict__ A, const u16* __restrict__ Bt,
             void* __restrict__ outp, int K, int ntn,
             const float* __restrict__ bias, const float* __restrict__ resid) {
  __shared__ u16 lds[3][12288];
  const int tid = threadIdx.x;
  const int wid = tid >> 6, lane = tid & 63;
  const int wm = wid >> 2, wn = wid & 3;
  const int g = lane >> 4, r = lane & 15;

  const int nwg = gridDim.x;
  const int orig = blockIdx.x;
  const int wg = (orig & 7) * (nwg >> 3) + (orig >> 3);  // XCD swizzle
  const int mt = wg / ntn, nt = wg - mt * ntn;
  const int row0 = mt * 128, col0 = nt * 256;

  const u16* Ag = A + (size_t)row0 * K;
  const u16* Bg = Bt + (size_t)col0 * K;
  const int NT = K >> 5;

  const int cx = (g * 8) ^ (((r >> 1) & 3) << 3);

  const int sa_row = tid >> 2;
  const int sa_sc = (tid & 3) ^ ((tid >> 3) & 3);
  const int sb_row1 = (tid + 512) >> 2;
  const int sb_sc1 = ((tid + 512) & 3) ^ (((tid + 512) >> 3) & 3);

  f32x4 acc[4][4] = {};

  auto stage = [&](int buf, int kt) {
    gll16(Ag + (size_t)sa_row * K + kt + sa_sc * 8, &lds[buf][tid * 8]);
    gll16(Bg + (size_t)sa_row * K + kt + sa_sc * 8, &lds[buf][4096 + tid * 8]);
    gll16(Bg + (size_t)sb_row1 * K + kt + sb_sc1 * 8,
          &lds[buf][4096 + (tid + 512) * 8]);
  };

  stage(0, 0);
  stage(1, 32);
  asm volatile("s_waitcnt vmcnt(3)" ::: "memory");
  SBAR();

  int buf = 0;
  for (int t = 0; t < NT; ++t) {
    int nb = buf + 2;
    if (nb >= 3) nb -= 3;
    if (t + 2 < NT) stage(nb, (t + 2) * 32);

    short8 a[4], b[4];
#pragma unroll
    for (int mi = 0; mi < 4; ++mi)
      a[mi] = *(short8*)&lds[buf][(wm * 64 + mi * 16 + r) * 32 + cx];
#pragma unroll
    for (int nf = 0; nf < 4; ++nf)
      b[nf] = *(short8*)&lds[buf][4096 + (wn * 64 + nf * 16 + r) * 32 + cx];

    __builtin_amdgcn_s_setprio(1);
#pragma unroll
    for (int mi = 0; mi < 4; ++mi)
#pragma unroll
      for (int nf = 0; nf < 4; ++nf)
        acc[mi][nf] = __builtin_amdgcn_mfma_f32_16x16x32_bf16(a[mi], b[nf],
                                                              acc[mi][nf], 0, 0, 0);
    __builtin_amdgcn_s_setprio(0);

    if (t < NT - 2)
      asm volatile("s_waitcnt vmcnt(3)" ::: "memory");
    else
      asm volatile("s_waitcnt vmcnt(0)" ::: "memory");
    SBAR();
    buf = (buf + 1 == 3) ? 0 : buf + 1;
  }

  if constexpr (MODE == 0) {
    u16* O = (u16*)outp;
#pragma unroll
    for (int mi = 0; mi < 4; ++mi)
#pragma unroll
      for (int i = 0; i < 4; ++i) {
        size_t m = row0 + wm * 64 + mi * 16 + g * 4 + i;
        size_t base = m * HDIM + col0 + wn * 64 + r;
#pragma unroll
        for (int nf = 0; nf < 4; ++nf)
          O[base + nf * 16] = f2bf(acc[mi][nf][i]);
      }
  } else {
    float* O = (float*)outp;
#pragma unroll
    for (int mi = 0; mi < 4; ++mi)
#pragma unroll
      for (int i = 0; i < 4; ++i) {
        size_t m = row0 + wm * 64 + mi * 16 + g * 4 + i;
        size_t base = m * HDIM + col0 + wn * 64 + r;
#pragma unroll
        for (int nf = 0; nf < 4; ++nf) {
          int col = col0 + wn * 64 + nf * 16 + r;
          O[base + nf * 16] = acc[mi][nf][i] + bias[col] + resid[base + nf * 16];
        }
      }
  }
}

// ---- merged K+V projection + hscvt. Blocks [0,80) = K-proj, [80,160) =
// V^T-proj (m97 structure); blocks >= 160 do the hs f32->bf16 convert
// (grid-stride). Branches are blockIdx-uniform.
__global__ __launch_bounds__(256, 4)
void gemm_kv_hs(const u16* __restrict__ A, const u16* __restrict__ Kt,
                const u16* __restrict__ Vt, u16* __restrict__ khb,
                u16* __restrict__ vtb, const float* __restrict__ hs,
                u16* __restrict__ hsb) {
  if (blockIdx.x >= 160) {
    const size_t total = (size_t)BB * SQ * HDIM;
    const int nb = gridDim.x - 160;
    size_t step = (size_t)nb * 256 * 8;
    for (size_t i = ((size_t)(blockIdx.x - 160) * 256 + threadIdx.x) * 8;
         i < total; i += step) {
      f32x4 a = *(const f32x4*)(hs + i);
      f32x4 b = *(const f32x4*)(hs + i + 4);
      short8 o;
#pragma unroll
      for (int j = 0; j < 4; j++) {
        o[j] = (short)f2bf(a[j]);
        o[j + 4] = (short)f2bf(b[j]);
      }
      *(short8*)&hsb[i] = o;
    }
    return;
  }

  __shared__ u16 Alds[128 * 32];
  __shared__ u16 Blds[128 * 32];
  const int tid = threadIdx.x;
  const int wid = tid >> 6, lane = tid & 63;
  const int wm = wid >> 1, wn = wid & 1;
  const int g = lane >> 4, r = lane & 15;

  const int half = blockIdx.x >= 80 ? 1 : 0;
  const u16* Bt = half ? Vt : Kt;
  const int orig = blockIdx.x - half * 80;
  const int wg = (orig & 7) * 10 + (orig >> 3);  // XCD swizzle within 80
  const int mt = wg / 10, nt = wg - mt * 10;
  const int row0 = mt * 128, col0 = nt * 128;
  const int erow = tid >> 2, ecol = (tid & 3) * 8;
  const int K = CDIM;

  f32x4 acc[4][4] = {};

  for (int kt = 0; kt < K; kt += 32) {
    const u16* ag = A + (size_t)(row0 + erow) * K + kt + ecol;
    const u16* bg = Bt + (size_t)(col0 + erow) * K + kt + ecol;
    gll16(ag, &Alds[erow * 32 + ecol]);
    gll16(ag + (size_t)64 * K, &Alds[(erow + 64) * 32 + ecol]);
    gll16(bg, &Blds[erow * 32 + ecol]);
    gll16(bg + (size_t)64 * K, &Blds[(erow + 64) * 32 + ecol]);
    __syncthreads();

    short8 afr[4], bfr[4];
#pragma unroll
    for (int mi = 0; mi < 4; mi++)
      afr[mi] = *(short8*)&Alds[(wm * 64 + mi * 16 + r) * 32 + g * 8];
#pragma unroll
    for (int ni = 0; ni < 4; ni++)
      bfr[ni] = *(short8*)&Blds[(wn * 64 + ni * 16 + r) * 32 + g * 8];
#pragma unroll
    for (int mi = 0; mi < 4; mi++)
#pragma unroll
      for (int ni = 0; ni < 4; ni++)
        acc[mi][ni] = __builtin_amdgcn_mfma_f32_16x16x32_bf16(afr[mi], bfr[ni],
                                                              acc[mi][ni], 0, 0, 0);
    __syncthreads();
  }

  u16* O = half ? vtb : khb;
#pragma unroll
  for (int mi = 0; mi < 4; mi++)
#pragma unroll
    for (int i = 0; i < 4; i++) {
      int m = row0 + wm * 64 + mi * 16 + g * 4 + i;
      int b = m >> 7, skv = m & 127;
#pragma unroll
      for (int ni = 0; ni < 4; ni++) {
        int col = col0 + wn * 64 + ni * 16 + r;
        int hh = col >> 6, d = col & 63;
        size_t addr;
        if (half)
          addr = (((size_t)b * HEADS + hh) * HD + d) * SKV_PAD + skv;
        else
          addr = (((size_t)b * HEADS + hh) * SKV_PAD + skv) * HD + d;
        O[addr] = f2bf(acc[mi][ni][i]);
      }
    }
}

// ---- fused attention v2: 8 Q-tiles/block; K/V staged once; per-wave P/Out
// regions -> no barriers in the Q-loop. Q prefetched one iteration ahead.
__global__ __launch_bounds__(256, 2)
void attn_kernel(const u16* __restrict__ q, const u16* __restrict__ kh,
                 const u16* __restrict__ vt, u16* __restrict__ o) {
  __shared__ u16 Klds[SKV_T * 72];     // [skv 112][64+8]
  __shared__ u16 Vlds[HD * 136];       // [64][128+8]
  __shared__ u16 Plds[4 * 16 * 136];   // per-wave P [16][136]
  __shared__ u16 Olds[4 * 16 * 72];    // per-wave out [16][72]
  const int tid = threadIdx.x;
  const int wid = tid >> 6, lane = tid & 63;
  const int g = lane >> 4, r = lane & 15;
  const int bh = blockIdx.y;
  const int b = bh / HEADS, h = bh - b * HEADS;
  const int qt0 = blockIdx.x * 8;

  const u16* kg = kh + (size_t)bh * SKV_PAD * HD;
  for (int i = tid; i < SKV_T * 8; i += 256) {
    int row = i >> 3, c = (i & 7) * 8;
    *(short8*)&Klds[row * 72 + c] = *(const short8*)(kg + row * HD + c);
  }
  const u16* vg = vt + (size_t)bh * HD * SKV_PAD;
  for (int i = tid; i < HD * 16; i += 256) {
    int row = i >> 4, c = (i & 15) * 8;
    *(short8*)&Vlds[row * 136 + c] = *(const short8*)(vg + row * SKV_PAD + c);
  }
  {
    short4v z = {0, 0, 0, 0};
    *(short4v*)&Plds[(wid * 16 + r) * 136 + 112 + g * 4] = z;
  }
  __syncthreads();

  const u16* qbase = q + ((size_t)b * SQ + wid * 16 + r) * HDIM + h * HD + g * 8;
  short8 aq0 = *(const short8*)(qbase + (size_t)qt0 * 64 * HDIM);
  short8 aq1 = *(const short8*)(qbase + (size_t)qt0 * 64 * HDIM + 32);

#pragma unroll 1
  for (int qs = 0; qs < 8; ++qs) {
    const int qt = qt0 + qs;

    f32x4 s[7];
#pragma unroll
    for (int nf = 0; nf < 7; nf++) {
      f32x4 z = {0.f, 0.f, 0.f, 0.f};
      short8 k0 = *(short8*)&Klds[(nf * 16 + r) * 72 + g * 8];
      short8 k1 = *(short8*)&Klds[(nf * 16 + r) * 72 + 32 + g * 8];
      z = __builtin_amdgcn_mfma_f32_16x16x32_bf16(aq0, k0, z, 0, 0, 0);
      z = __builtin_amdgcn_mfma_f32_16x16x32_bf16(aq1, k1, z, 0, 0, 0);
      s[nf] = z;
    }

    if (qs + 1 < 8) {
      aq0 = *(const short8*)(qbase + (size_t)(qt + 1) * 64 * HDIM);
      aq1 = *(const short8*)(qbase + (size_t)(qt + 1) * 64 * HDIM + 32);
    }

#pragma unroll
    for (int i = 0; i < 4; i++) {
      float pv[7];
      float mx = -1e30f;
#pragma unroll
      for (int nf = 0; nf < 7; nf++) {
        float v = s[nf][i];
        if (nf == 6 && r >= 13) v = -1e30f;  // cols >= 109 masked
        pv[nf] = v;
        mx = fmaxf(mx, v);
      }
#pragma unroll
      for (int d = 1; d < 16; d <<= 1) mx = fmaxf(mx, __shfl_xor(mx, d, 64));
      float sum = 0.f;
#pragma unroll
      for (int nf = 0; nf < 7; nf++) {
        float e = (nf == 6 && r >= 13) ? 0.f : __expf(pv[nf] - mx);
        pv[nf] = e;
        sum += e;
      }
#pragma unroll
      for (int d = 1; d < 16; d <<= 1) sum += __shfl_xor(sum, d, 64);
      float is = 1.f / sum;
#pragma unroll
      for (int nf = 0; nf < 7; nf++)
        Plds[(wid * 16 + g * 4 + i) * 136 + nf * 16 + r] = f2bf(pv[nf] * is);
    }

    f32x4 oacc[4] = {};
#pragma unroll
    for (int kk = 0; kk < 4; kk++) {
      short8 ap = *(short8*)&Plds[(wid * 16 + r) * 136 + kk * 32 + g * 8];
#pragma unroll
      for (int nf = 0; nf < 4; nf++) {
        short8 bv = *(short8*)&Vlds[(nf * 16 + r) * 136 + kk * 32 + g * 8];
        oacc[nf] = __builtin_amdgcn_mfma_f32_16x16x32_bf16(ap, bv, oacc[nf], 0, 0, 0);
      }
    }

    u16* st = &Olds[wid * 16 * 72];
#pragma unroll
    for (int nf = 0; nf < 4; nf++)
#pragma unroll
      for (int i = 0; i < 4; i++)
        st[(g * 4 + i) * 72 + nf * 16 + r] = f2bf(oacc[nf][i]);
    u16* og = o + ((size_t)b * SQ + qt * 64 + wid * 16) * HDIM + h * HD;
#pragma unroll
    for (int j = 0; j < 2; ++j) {
      int chunk = lane + j * 64;
      int row = chunk >> 3, cc = (chunk & 7) * 8;
      *(short8*)&og[(size_t)row * HDIM + cc] = *(short8*)&st[row * 72 + cc];
    }
  }
}

extern "C" void kernel_launch(void* const* d_in, const int* in_sizes, int n_in,
                              void* d_out, int out_size, void* d_ws, size_t ws_size,
                              hipStream_t stream) {
  const float* hs  = (const float*)d_in[0];
  const float* ehs = (const float*)d_in[1];
  const float* Wq  = (const float*)d_in[2];
  const float* Wk  = (const float*)d_in[3];
  const float* Wv  = (const float*)d_in[4];
  const float* Wo  = (const float*)d_in[5];
  const float* bo  = (const float*)d_in[6];

  char* ws = (char*)d_ws;
  size_t off = 0;
  auto alloc = [&](size_t elems) {
    u16* p = (u16*)(ws + off);
    off += ((elems * 2 + 255) / 256) * 256;
    return p;
  };
  u16* wqt  = alloc((size_t)HDIM * HDIM);
  u16* wot  = alloc((size_t)HDIM * HDIM);
  u16* wkt  = alloc((size_t)HDIM * CDIM);
  u16* wvt  = alloc((size_t)HDIM * CDIM);
  u16* ehsp = alloc((size_t)BB * SKV_PAD * CDIM);
  u16* khb  = alloc((size_t)BB * HEADS * SKV_PAD * HD);
  u16* vtb  = alloc((size_t)BB * HEADS * HD * SKV_PAD);
  u16* qb   = alloc((size_t)BB * SQ * HDIM);
  u16* ao   = alloc((size_t)BB * SQ * HDIM);
  u16* hsb  = ao;  // alias: hsb dead before attention writes ao

  // merged prep: 4 weight transposes + encoder pad (5888 blocks)
  prep_all<<<dim3(5888), 256, 0, stream>>>(Wq, Wk, Wv, Wo, ehs, wqt, wkt, wvt,
                                           wot, ehsp);
  // merged K,V projections + hs->bf16 convert (160 GEMM blocks + 1888 cvt)
  gemm_kv_hs<<<dim3(2048), 256, 0, stream>>>(ehsp, wkt, wvt, khb, vtb, hs, hsb);
  // Q projection: 128x256 3-buf counted-vmcnt (grid 1280 % 8 == 0)
  gemm_v2<0><<<dim3(1280), 512, 0, stream>>>(hsb, wqt, qb, HDIM, 5, nullptr, nullptr);
  // attention: 8 Q-tiles per block, K/V staged once
  attn_kernel<<<dim3(SQ / 512, BB * HEADS), 256, 0, stream>>>(qb, khb, vtb, ao);
  // output projection + bias + f32 residual
  gemm_v2<3><<<dim3(1280), 512, 0, stream>>>(ao, wot, (void*)d_out, HDIM, 5, bo, hs);
}